// Round 5
// baseline (1615.010 us; speedup 1.0000x reference)
//
#include <hip/hip_runtime.h>
#include <cstddef>

#define NN 100000
#define NE 1600000

// ===========================================================================
// CSR build: histogram(dst) -> exclusive scan -> scatter {e, src} records
// ===========================================================================
__global__ __launch_bounds__(256) void hist_dst(const int* __restrict__ ei,
                                                int* __restrict__ deg)
{
    int i = blockIdx.x * 256 + threadIdx.x;
    int stride = gridDim.x * 256;
    for (int e = i; e < NE; e += stride)
        atomicAdd(&deg[ei[NE + e]], 1);
}

// Single-block exclusive scan over NN degrees, wave-shuffle based.
// Writes off[0..NN] and rewrites deg[i] = off[i] (scatter cursor).
__global__ __launch_bounds__(1024) void scan_deg(int* __restrict__ deg,
                                                 int* __restrict__ off)
{
    __shared__ int swsum[16];
    __shared__ int stot;
    __shared__ int carry_s;
    int t = threadIdx.x;
    int lane = t & 63, wid = t >> 6;
    if (t == 0) carry_s = 0;
    __syncthreads();
    for (int base = 0; base < NN; base += 1024) {
        int i = base + t;
        int v = (i < NN) ? deg[i] : 0;
        int incl = v;
        #pragma unroll
        for (int o = 1; o < 64; o <<= 1) {
            int u = __shfl_up(incl, o, 64);
            if (lane >= o) incl += u;
        }
        if (lane == 63) swsum[wid] = incl;
        __syncthreads();
        if (wid == 0) {
            int wv = (lane < 16) ? swsum[lane] : 0;
            int wincl = wv;
            #pragma unroll
            for (int o = 1; o < 16; o <<= 1) {
                int u = __shfl_up(wincl, o, 64);
                if (lane >= o) wincl += u;
            }
            if (lane < 16) swsum[lane] = wincl - wv;   // exclusive wave offset
            if (lane == 15) stot = wincl;              // chunk total
        }
        __syncthreads();
        int excl = carry_s + swsum[wid] + (incl - v);
        if (i < NN) { off[i] = excl; deg[i] = excl; }
        __syncthreads();
        if (t == 0) carry_s += stot;
        __syncthreads();
    }
    if (t == 0) off[NN] = carry_s;
}

__global__ __launch_bounds__(256) void scatter_perm(const int* __restrict__ ei,
                                                    int* __restrict__ cur,
                                                    int2* __restrict__ perm2)
{
    int i = blockIdx.x * 256 + threadIdx.x;
    int stride = gridDim.x * 256;
    for (int e = i; e < NE; e += stride) {
        int s = ei[e];
        int d = ei[NE + e];
        int pos = atomicAdd(&cur[d], 1);
        perm2[pos] = make_int2(e, s);
    }
}

// ===========================================================================
// conv1 gather: persistent waves, work-stealing batches of 4 nodes.
// One FULL wave per node (wave-uniform => readfirstlane legal),
// 2 channels/lane (128 ch), 2-deep software pipeline.
// aggr1[n] = sum_{e: dst=n} relu(x[src_e] + ea[e] @ We1 + be1)
// ===========================================================================
__global__ __launch_bounds__(256) void conv1_gather(
    const float* __restrict__ x, const float* __restrict__ ea,
    const float* __restrict__ We, const float* __restrict__ be,
    const int* __restrict__ off, const int2* __restrict__ perm2,
    float* __restrict__ aggr, int* __restrict__ counter)
{
    __shared__ float2 sWe[16 * 64];
    __shared__ float2 sbe[64];
    int t = threadIdx.x;
    const float2* W2 = (const float2*)We;
    for (int i = t; i < 1024; i += 256) sWe[i] = W2[i];
    if (t < 64) sbe[t] = ((const float2*)be)[t];
    __syncthreads();

    int lane = t & 63;
    while (true) {
        int base = 0;
        if (lane == 0) base = atomicAdd(counter, 4);
        base = __shfl(base, 0, 64);
        if (base >= NN) break;
        int nend = (base + 4 < NN) ? base + 4 : NN;
        for (int n = base; n < nend; n++) {
            int j0 = off[n], j1 = off[n + 1];
            float2 bias = sbe[lane];
            float2 acc = make_float2(0.f, 0.f);

            int2 es1 = make_int2(0, 0);
            float4 c0, c1, c2, c3; float2 cx;
            c0 = c1 = c2 = c3 = make_float4(0.f, 0.f, 0.f, 0.f);
            cx = make_float2(0.f, 0.f);
            if (j0 < j1) {
                int2 es0 = perm2[j0];
                int e = __builtin_amdgcn_readfirstlane(es0.x);
                int s = __builtin_amdgcn_readfirstlane(es0.y);
                const float4* ap = (const float4*)(ea + (size_t)e * 16);
                c0 = ap[0]; c1 = ap[1]; c2 = ap[2]; c3 = ap[3];
                cx = *(const float2*)(x + (size_t)s * 128 + (lane << 1));
                if (j0 + 1 < j1) es1 = perm2[j0 + 1];
            }
            for (int j = j0; j < j1; j++) {
                float4 p0, p1, p2, p3; float2 px; int2 es2 = es1;
                p0 = c0; p1 = c1; p2 = c2; p3 = c3; px = cx;
                if (j + 1 < j1) {
                    int e = __builtin_amdgcn_readfirstlane(es1.x);
                    int s = __builtin_amdgcn_readfirstlane(es1.y);
                    const float4* ap = (const float4*)(ea + (size_t)e * 16);
                    p0 = ap[0]; p1 = ap[1]; p2 = ap[2]; p3 = ap[3];
                    px = *(const float2*)(x + (size_t)s * 128 + (lane << 1));
                    if (j + 2 < j1) es2 = perm2[j + 2];
                }
                float av[16] = {c0.x,c0.y,c0.z,c0.w, c1.x,c1.y,c1.z,c1.w,
                                c2.x,c2.y,c2.z,c2.w, c3.x,c3.y,c3.z,c3.w};
                float2 m = bias;
                #pragma unroll
                for (int k = 0; k < 16; k++) {
                    float2 w = sWe[(k << 6) + lane];
                    m.x = fmaf(av[k], w.x, m.x);
                    m.y = fmaf(av[k], w.y, m.y);
                }
                acc.x += fmaxf(cx.x + m.x, 0.0f);
                acc.y += fmaxf(cx.y + m.y, 0.0f);
                c0 = p0; c1 = p1; c2 = p2; c3 = p3; cx = px;
                es1 = es2;
            }
            *(float2*)(aggr + (size_t)n * 128 + (lane << 1)) = acc;
        }
    }
}

// ===========================================================================
// conv_mu + conv_logstd gather, fused: persistent work-stealing waves,
// one FULL wave per node. Trees split across the wave: lanes 0-31 = mu (W2),
// lanes 32-63 = logstd (W3), 2 channels/lane. 2-deep pipeline.
// ===========================================================================
__global__ __launch_bounds__(256) void conv23_gather(
    const float* __restrict__ h, const float* __restrict__ ea,
    const float* __restrict__ We2, const float* __restrict__ be2,
    const float* __restrict__ We3, const float* __restrict__ be3,
    const int* __restrict__ off, const int2* __restrict__ perm2,
    float* __restrict__ aggr2, float* __restrict__ aggr3,
    int* __restrict__ counter)
{
    // row k of sW holds [ W2 row k : 32 float2 | W3 row k : 32 float2 ]
    __shared__ float2 sW[16 * 64];
    __shared__ float2 sb[64];
    int t = threadIdx.x;
    for (int i = t; i < 512; i += 256) {
        int k = i >> 5, c = i & 31;
        sW[(k << 6) + c]      = ((const float2*)We2)[i];
        sW[(k << 6) + 32 + c] = ((const float2*)We3)[i];
    }
    if (t < 32) { sb[t] = ((const float2*)be2)[t]; sb[32 + t] = ((const float2*)be3)[t]; }
    __syncthreads();

    int lane = t & 63;
    int half = lane >> 5;            // 0 = mu tree, 1 = logstd tree
    int c2 = (lane & 31) << 1;       // channel pair within the tree
    while (true) {
        int base = 0;
        if (lane == 0) base = atomicAdd(counter, 4);
        base = __shfl(base, 0, 64);
        if (base >= NN) break;
        int nend = (base + 4 < NN) ? base + 4 : NN;
        for (int n = base; n < nend; n++) {
            int j0 = off[n], j1 = off[n + 1];
            float2 bias = sb[lane];
            float2 acc = make_float2(0.f, 0.f);

            int2 es1 = make_int2(0, 0);
            float4 c0, c1, c2v, c3; float2 ch;
            c0 = c1 = c2v = c3 = make_float4(0.f, 0.f, 0.f, 0.f);
            ch = make_float2(0.f, 0.f);
            if (j0 < j1) {
                int2 es0 = perm2[j0];
                int e = __builtin_amdgcn_readfirstlane(es0.x);
                int s = __builtin_amdgcn_readfirstlane(es0.y);
                const float4* ap = (const float4*)(ea + (size_t)e * 16);
                c0 = ap[0]; c1 = ap[1]; c2v = ap[2]; c3 = ap[3];
                ch = *(const float2*)(h + (size_t)s * 64 + c2);
                if (j0 + 1 < j1) es1 = perm2[j0 + 1];
            }
            for (int j = j0; j < j1; j++) {
                float4 p0, p1, p2, p3; float2 ph; int2 es2 = es1;
                p0 = c0; p1 = c1; p2 = c2v; p3 = c3; ph = ch;
                if (j + 1 < j1) {
                    int e = __builtin_amdgcn_readfirstlane(es1.x);
                    int s = __builtin_amdgcn_readfirstlane(es1.y);
                    const float4* ap = (const float4*)(ea + (size_t)e * 16);
                    p0 = ap[0]; p1 = ap[1]; p2 = ap[2]; p3 = ap[3];
                    ph = *(const float2*)(h + (size_t)s * 64 + c2);
                    if (j + 2 < j1) es2 = perm2[j + 2];
                }
                float av[16] = {c0.x,c0.y,c0.z,c0.w, c1.x,c1.y,c1.z,c1.w,
                                c2v.x,c2v.y,c2v.z,c2v.w, c3.x,c3.y,c3.z,c3.w};
                float2 m = bias;
                #pragma unroll
                for (int k = 0; k < 16; k++) {
                    float2 w = sW[(k << 6) + lane];
                    m.x = fmaf(av[k], w.x, m.x);
                    m.y = fmaf(av[k], w.y, m.y);
                }
                acc.x += fmaxf(ch.x + m.x, 0.0f);
                acc.y += fmaxf(ch.y + m.y, 0.0f);
                c0 = p0; c1 = p1; c2v = p2; c3 = p3; ch = ph;
                es1 = es2;
            }
            float* dstp = (half ? aggr3 : aggr2) + (size_t)n * 64 + c2;
            *(float2*)dstp = acc;
        }
    }
}

// ===========================================================================
// Node MLP: out = epilogue( relu((xin+aggr) @ Wa + ba) @ Wb + bb )
// KIN -> 64 -> 64. 64 nodes per block, 256 threads, 4x4 register tiles.
// mode: 0 = none, 1 = relu, 2 = clip(-10, 10)
// ===========================================================================
template <int KIN>
__global__ __launch_bounds__(256) void node_mlp(
    const float* __restrict__ xin, const float* __restrict__ aggr,
    const float* __restrict__ Wa, const float* __restrict__ ba,
    const float* __restrict__ Wb, const float* __restrict__ bb,
    float* __restrict__ out, int mode)
{
    constexpr int S0 = KIN + 4;
    constexpr int K4 = KIN / 4;
    __shared__ float sWa[KIN * 64];
    __shared__ float sWb[64 * 64];
    __shared__ float sh[64 * S0];
    __shared__ float sba[64], sbb[64];
    int t = threadIdx.x;
    for (int i = t; i < KIN * 16; i += 256) ((float4*)sWa)[i] = ((const float4*)Wa)[i];
    for (int i = t; i < 1024; i += 256)     ((float4*)sWb)[i] = ((const float4*)Wb)[i];
    if (t < 64) { sba[t] = ba[t]; sbb[t] = bb[t]; }

    int nb = blockIdx.x << 6;
    for (int i = t; i < 64 * K4; i += 256) {
        int n = i / K4, k4 = i % K4;
        int node = nb + n;
        float4 v = make_float4(0.f, 0.f, 0.f, 0.f);
        if (node < NN) {
            float4 a = ((const float4*)(xin  + (size_t)node * KIN))[k4];
            float4 b = ((const float4*)(aggr + (size_t)node * KIN))[k4];
            v = make_float4(a.x + b.x, a.y + b.y, a.z + b.z, a.w + b.w);
        }
        *(float4*)&sh[n * S0 + (k4 << 2)] = v;
    }
    __syncthreads();

    int tx = t & 15, ty = t >> 4;
    int c0 = tx << 2, n0 = ty << 2;

    float4 b1 = *(const float4*)&sba[c0];
    float acc[4][4];
    #pragma unroll
    for (int i = 0; i < 4; i++) { acc[i][0] = b1.x; acc[i][1] = b1.y; acc[i][2] = b1.z; acc[i][3] = b1.w; }
    for (int k4 = 0; k4 < K4; k4++) {
        int k = k4 << 2;
        float4 w0 = *(const float4*)&sWa[((k + 0) << 6) + c0];
        float4 w1 = *(const float4*)&sWa[((k + 1) << 6) + c0];
        float4 w2 = *(const float4*)&sWa[((k + 2) << 6) + c0];
        float4 w3 = *(const float4*)&sWa[((k + 3) << 6) + c0];
        #pragma unroll
        for (int i = 0; i < 4; i++) {
            float4 hv = *(const float4*)&sh[(n0 + i) * S0 + k];
            acc[i][0] = fmaf(hv.x, w0.x, acc[i][0]); acc[i][1] = fmaf(hv.x, w0.y, acc[i][1]);
            acc[i][2] = fmaf(hv.x, w0.z, acc[i][2]); acc[i][3] = fmaf(hv.x, w0.w, acc[i][3]);
            acc[i][0] = fmaf(hv.y, w1.x, acc[i][0]); acc[i][1] = fmaf(hv.y, w1.y, acc[i][1]);
            acc[i][2] = fmaf(hv.y, w1.z, acc[i][2]); acc[i][3] = fmaf(hv.y, w1.w, acc[i][3]);
            acc[i][0] = fmaf(hv.z, w2.x, acc[i][0]); acc[i][1] = fmaf(hv.z, w2.y, acc[i][1]);
            acc[i][2] = fmaf(hv.z, w2.z, acc[i][2]); acc[i][3] = fmaf(hv.z, w2.w, acc[i][3]);
            acc[i][0] = fmaf(hv.w, w3.x, acc[i][0]); acc[i][1] = fmaf(hv.w, w3.y, acc[i][1]);
            acc[i][2] = fmaf(hv.w, w3.z, acc[i][2]); acc[i][3] = fmaf(hv.w, w3.w, acc[i][3]);
        }
    }
    __syncthreads();
    #pragma unroll
    for (int i = 0; i < 4; i++) {
        float4 v = make_float4(fmaxf(acc[i][0], 0.f), fmaxf(acc[i][1], 0.f),
                               fmaxf(acc[i][2], 0.f), fmaxf(acc[i][3], 0.f));
        *(float4*)&sh[(n0 + i) * 68 + c0] = v;
    }
    __syncthreads();

    float4 b2 = *(const float4*)&sbb[c0];
    float acc2[4][4];
    #pragma unroll
    for (int i = 0; i < 4; i++) { acc2[i][0] = b2.x; acc2[i][1] = b2.y; acc2[i][2] = b2.z; acc2[i][3] = b2.w; }
    for (int k4 = 0; k4 < 16; k4++) {
        int k = k4 << 2;
        float4 w0 = *(const float4*)&sWb[((k + 0) << 6) + c0];
        float4 w1 = *(const float4*)&sWb[((k + 1) << 6) + c0];
        float4 w2 = *(const float4*)&sWb[((k + 2) << 6) + c0];
        float4 w3 = *(const float4*)&sWb[((k + 3) << 6) + c0];
        #pragma unroll
        for (int i = 0; i < 4; i++) {
            float4 hv = *(const float4*)&sh[(n0 + i) * 68 + k];
            acc2[i][0] = fmaf(hv.x, w0.x, acc2[i][0]); acc2[i][1] = fmaf(hv.x, w0.y, acc2[i][1]);
            acc2[i][2] = fmaf(hv.x, w0.z, acc2[i][2]); acc2[i][3] = fmaf(hv.x, w0.w, acc2[i][3]);
            acc2[i][0] = fmaf(hv.y, w1.x, acc2[i][0]); acc2[i][1] = fmaf(hv.y, w1.y, acc2[i][1]);
            acc2[i][2] = fmaf(hv.y, w1.z, acc2[i][2]); acc2[i][3] = fmaf(hv.y, w1.w, acc2[i][3]);
            acc2[i][0] = fmaf(hv.z, w2.x, acc2[i][0]); acc2[i][1] = fmaf(hv.z, w2.y, acc2[i][1]);
            acc2[i][2] = fmaf(hv.z, w2.z, acc2[i][2]); acc2[i][3] = fmaf(hv.z, w2.w, acc2[i][3]);
            acc2[i][0] = fmaf(hv.w, w3.x, acc2[i][0]); acc2[i][1] = fmaf(hv.w, w3.y, acc2[i][1]);
            acc2[i][2] = fmaf(hv.w, w3.z, acc2[i][2]); acc2[i][3] = fmaf(hv.w, w3.w, acc2[i][3]);
        }
    }

    #pragma unroll
    for (int i = 0; i < 4; i++) {
        int node = nb + n0 + i;
        if (node >= NN) continue;
        float4 v = make_float4(acc2[i][0], acc2[i][1], acc2[i][2], acc2[i][3]);
        if (mode == 1) {
            v = make_float4(fmaxf(v.x, 0.f), fmaxf(v.y, 0.f), fmaxf(v.z, 0.f), fmaxf(v.w, 0.f));
        } else if (mode == 2) {
            v = make_float4(fminf(fmaxf(v.x, -10.f), 10.f), fminf(fmaxf(v.y, -10.f), 10.f),
                            fminf(fmaxf(v.z, -10.f), 10.f), fminf(fmaxf(v.w, -10.f), 10.f));
        }
        *(float4*)(out + (size_t)node * 64 + c0) = v;
    }
}

extern "C" void kernel_launch(void* const* d_in, const int* in_sizes, int n_in,
                              void* d_out, int out_size, void* d_ws, size_t ws_size,
                              hipStream_t stream)
{
    const float* x   = (const float*)d_in[0];
    const int*   ei  = (const int*)  d_in[1];
    const float* ea  = (const float*)d_in[2];
    const float* We1 = (const float*)d_in[3];
    const float* be1 = (const float*)d_in[4];
    const float* W1a = (const float*)d_in[5];
    const float* b1a = (const float*)d_in[6];
    const float* W1b = (const float*)d_in[7];
    const float* b1b = (const float*)d_in[8];
    const float* We2 = (const float*)d_in[9];
    const float* be2 = (const float*)d_in[10];
    const float* W2a = (const float*)d_in[11];
    const float* b2a = (const float*)d_in[12];
    const float* W2b = (const float*)d_in[13];
    const float* b2b = (const float*)d_in[14];
    const float* We3 = (const float*)d_in[15];
    const float* be3 = (const float*)d_in[16];
    const float* W3a = (const float*)d_in[17];
    const float* b3a = (const float*)d_in[18];
    const float* W3b = (const float*)d_in[19];
    const float* b3b = (const float*)d_in[20];

    float* out = (float*)d_out;
    float* ws = (float*)d_ws;
    // float scratch: aggr1 [12.8M] (later aliased by aggr2/aggr3), h [6.4M]
    float* aggr1 = ws;
    float* h     = ws + 12800000;
    float* aggr2 = ws;              // aliases aggr1 (dead after node_mlp<128>)
    float* aggr3 = ws + 6400000;
    // int scratch after 19.2M floats: off [NN+1], cur [NN], perm2 [2*NE], counters [2]
    int* ibase = (int*)(ws + 19200000);
    int* off   = ibase;
    int* cur   = ibase + (NN + 1);
    int2* perm2 = (int2*)(ibase + (2 * NN + 2));
    int* counters = ibase + (2 * NN + 2) + 2 * NE;

    // ---- CSR build (shared by conv1 and conv23) ----
    hipMemsetAsync(cur, 0, (size_t)NN * sizeof(int), stream);
    hipMemsetAsync(counters, 0, 2 * sizeof(int), stream);
    hist_dst<<<2048, 256, 0, stream>>>(ei, cur);
    scan_deg<<<1, 1024, 0, stream>>>(cur, off);   // cur becomes scatter cursor
    scatter_perm<<<2048, 256, 0, stream>>>(ei, cur, perm2);

    // ---- layer 1 ----
    conv1_gather<<<2048, 256, 0, stream>>>(x, ea, We1, be1, off, perm2, aggr1,
                                           counters + 0);
    node_mlp<128><<<(NN + 63) / 64, 256, 0, stream>>>(x, aggr1, W1a, b1a, W1b, b1b, h, 1);

    // ---- layers 2+3 (fused edge pass) ----
    conv23_gather<<<2048, 256, 0, stream>>>(h, ea, We2, be2, We3, be3,
                                            off, perm2, aggr2, aggr3, counters + 1);
    node_mlp<64><<<(NN + 63) / 64, 256, 0, stream>>>(h, aggr2, W2a, b2a, W2b, b2b, out, 0);
    node_mlp<64><<<(NN + 63) / 64, 256, 0, stream>>>(h, aggr3, W3a, b3a, W3b, b3b,
                                                     out + (size_t)NN * 64, 2);
}

// Round 6
// 1457.710 us; speedup vs baseline: 1.1079x; 1.1079x over previous
//
#include <hip/hip_runtime.h>
#include <cstddef>

#define NN 100000
#define NE 1600000

// ===========================================================================
// CSR build: histogram(dst) -> exclusive scan -> scatter {e, src} records
// ===========================================================================
__global__ __launch_bounds__(256) void hist_dst(const int* __restrict__ ei,
                                                int* __restrict__ deg)
{
    int i = blockIdx.x * 256 + threadIdx.x;
    int stride = gridDim.x * 256;
    for (int e = i; e < NE; e += stride)
        atomicAdd(&deg[ei[NE + e]], 1);
}

// Single-block exclusive scan over NN degrees, wave-shuffle based.
__global__ __launch_bounds__(1024) void scan_deg(int* __restrict__ deg,
                                                 int* __restrict__ off)
{
    __shared__ int swsum[16];
    __shared__ int stot;
    __shared__ int carry_s;
    int t = threadIdx.x;
    int lane = t & 63, wid = t >> 6;
    if (t == 0) carry_s = 0;
    __syncthreads();
    for (int base = 0; base < NN; base += 1024) {
        int i = base + t;
        int v = (i < NN) ? deg[i] : 0;
        int incl = v;
        #pragma unroll
        for (int o = 1; o < 64; o <<= 1) {
            int u = __shfl_up(incl, o, 64);
            if (lane >= o) incl += u;
        }
        if (lane == 63) swsum[wid] = incl;
        __syncthreads();
        if (wid == 0) {
            int wv = (lane < 16) ? swsum[lane] : 0;
            int wincl = wv;
            #pragma unroll
            for (int o = 1; o < 16; o <<= 1) {
                int u = __shfl_up(wincl, o, 64);
                if (lane >= o) wincl += u;
            }
            if (lane < 16) swsum[lane] = wincl - wv;
            if (lane == 15) stot = wincl;
        }
        __syncthreads();
        int excl = carry_s + swsum[wid] + (incl - v);
        if (i < NN) { off[i] = excl; deg[i] = excl; }
        __syncthreads();
        if (t == 0) carry_s += stot;
        __syncthreads();
    }
    if (t == 0) off[NN] = carry_s;
}

__global__ __launch_bounds__(256) void scatter_perm(const int* __restrict__ ei,
                                                    int* __restrict__ cur,
                                                    int2* __restrict__ perm2)
{
    int i = blockIdx.x * 256 + threadIdx.x;
    int stride = gridDim.x * 256;
    for (int e = i; e < NE; e += stride) {
        int s = ei[e];
        int d = ei[NE + e];
        int pos = atomicAdd(&cur[d], 1);
        perm2[pos] = make_int2(e, s);
    }
}

// ===========================================================================
// conv1 gather: one FULL wave per node, static node assignment.
// Weights hoisted to registers; edge records batch-loaded (64/chunk) and
// distributed via __shfl; depth-4 static-slot software pipeline.
// aggr1[n] = sum_{e: dst=n} relu(x[src_e] + ea[e] @ We1 + be1)
// ===========================================================================
__global__ __launch_bounds__(256) void conv1_gather(
    const float* __restrict__ x, const float* __restrict__ ea,
    const float* __restrict__ We, const float* __restrict__ be,
    const int* __restrict__ off, const int2* __restrict__ perm2,
    float* __restrict__ aggr)
{
    __shared__ float2 sWe[16 * 64];
    __shared__ float2 sbe[64];
    int t = threadIdx.x;
    const float2* W2 = (const float2*)We;
    for (int i = t; i < 1024; i += 256) sWe[i] = W2[i];
    if (t < 64) sbe[t] = ((const float2*)be)[t];
    __syncthreads();

    int lane = t & 63;
    int n = blockIdx.x * 4 + (t >> 6);
    if (n >= NN) return;

    // hoist weights + bias into registers: inner loop has no LDS traffic
    float2 wreg[16];
    #pragma unroll
    for (int k = 0; k < 16; k++) wreg[k] = sWe[(k << 6) + lane];
    float2 bias = sbe[lane];

    int j0 = off[n], j1 = off[n + 1];
    int cnt = j1 - j0;
    float2 acc = make_float2(0.f, 0.f);

    float4 A0[4], A1[4], A2[4], A3[4];
    float2 X[4];

    for (int cb = 0; cb < cnt; cb += 64) {
        int m = cnt - cb; if (m > 64) m = 64;
        // one coalesced load: up to 64 edge records for this node chunk
        int jl = j0 + cb + ((lane < m) ? lane : (m - 1));
        int2 es = perm2[jl];
        int esx = es.x, esy = es.y;

        auto issue = [&](int slot, int idx) {
            int ii = (idx < m - 1) ? idx : (m - 1);
            int e = __shfl(esx, ii, 64);
            int s = __shfl(esy, ii, 64);
            const float4* ap = (const float4*)(ea + (size_t)(unsigned)e * 16);
            A0[slot] = ap[0]; A1[slot] = ap[1]; A2[slot] = ap[2]; A3[slot] = ap[3];
            X[slot] = *(const float2*)(x + (size_t)(unsigned)s * 128 + (lane << 1));
        };
        auto compute = [&](int slot) {
            float av[16] = {A0[slot].x, A0[slot].y, A0[slot].z, A0[slot].w,
                            A1[slot].x, A1[slot].y, A1[slot].z, A1[slot].w,
                            A2[slot].x, A2[slot].y, A2[slot].z, A2[slot].w,
                            A3[slot].x, A3[slot].y, A3[slot].z, A3[slot].w};
            float2 mm = bias;
            #pragma unroll
            for (int k = 0; k < 16; k++) {
                mm.x = fmaf(av[k], wreg[k].x, mm.x);
                mm.y = fmaf(av[k], wreg[k].y, mm.y);
            }
            acc.x += fmaxf(X[slot].x + mm.x, 0.0f);
            acc.y += fmaxf(X[slot].y + mm.y, 0.0f);
        };

        issue(0, 0); issue(1, 1); issue(2, 2); issue(3, 3);
        for (int i = 0; i < m; i += 4) {
            #pragma unroll
            for (int s = 0; s < 4; s++) {
                if (i + s < m) {            // wave-uniform predicate
                    compute(s);
                    issue(s, i + s + 4);
                }
            }
        }
    }
    *(float2*)(aggr + (size_t)n * 128 + (lane << 1)) = acc;
}

// ===========================================================================
// conv_mu + conv_logstd gather, fused: one FULL wave per node; lanes 0-31 =
// mu (W2), lanes 32-63 = logstd (W3), 2 ch/lane. Same batched + depth-4
// pipeline structure as conv1_gather.
// ===========================================================================
__global__ __launch_bounds__(256) void conv23_gather(
    const float* __restrict__ h, const float* __restrict__ ea,
    const float* __restrict__ We2, const float* __restrict__ be2,
    const float* __restrict__ We3, const float* __restrict__ be3,
    const int* __restrict__ off, const int2* __restrict__ perm2,
    float* __restrict__ aggr2, float* __restrict__ aggr3)
{
    // row k of sW holds [ W2 row k : 32 float2 | W3 row k : 32 float2 ]
    __shared__ float2 sW[16 * 64];
    __shared__ float2 sb[64];
    int t = threadIdx.x;
    for (int i = t; i < 512; i += 256) {
        int k = i >> 5, c = i & 31;
        sW[(k << 6) + c]      = ((const float2*)We2)[i];
        sW[(k << 6) + 32 + c] = ((const float2*)We3)[i];
    }
    if (t < 32) { sb[t] = ((const float2*)be2)[t]; sb[32 + t] = ((const float2*)be3)[t]; }
    __syncthreads();

    int lane = t & 63;
    int half = lane >> 5;            // 0 = mu tree, 1 = logstd tree
    int c2 = (lane & 31) << 1;       // channel pair within the tree
    int n = blockIdx.x * 4 + (t >> 6);
    if (n >= NN) return;

    float2 wreg[16];
    #pragma unroll
    for (int k = 0; k < 16; k++) wreg[k] = sW[(k << 6) + lane];
    float2 bias = sb[lane];

    int j0 = off[n], j1 = off[n + 1];
    int cnt = j1 - j0;
    float2 acc = make_float2(0.f, 0.f);

    float4 A0[4], A1[4], A2[4], A3[4];
    float2 X[4];

    for (int cb = 0; cb < cnt; cb += 64) {
        int m = cnt - cb; if (m > 64) m = 64;
        int jl = j0 + cb + ((lane < m) ? lane : (m - 1));
        int2 es = perm2[jl];
        int esx = es.x, esy = es.y;

        auto issue = [&](int slot, int idx) {
            int ii = (idx < m - 1) ? idx : (m - 1);
            int e = __shfl(esx, ii, 64);
            int s = __shfl(esy, ii, 64);
            const float4* ap = (const float4*)(ea + (size_t)(unsigned)e * 16);
            A0[slot] = ap[0]; A1[slot] = ap[1]; A2[slot] = ap[2]; A3[slot] = ap[3];
            X[slot] = *(const float2*)(h + (size_t)(unsigned)s * 64 + c2);
        };
        auto compute = [&](int slot) {
            float av[16] = {A0[slot].x, A0[slot].y, A0[slot].z, A0[slot].w,
                            A1[slot].x, A1[slot].y, A1[slot].z, A1[slot].w,
                            A2[slot].x, A2[slot].y, A2[slot].z, A2[slot].w,
                            A3[slot].x, A3[slot].y, A3[slot].z, A3[slot].w};
            float2 mm = bias;
            #pragma unroll
            for (int k = 0; k < 16; k++) {
                mm.x = fmaf(av[k], wreg[k].x, mm.x);
                mm.y = fmaf(av[k], wreg[k].y, mm.y);
            }
            acc.x += fmaxf(X[slot].x + mm.x, 0.0f);
            acc.y += fmaxf(X[slot].y + mm.y, 0.0f);
        };

        issue(0, 0); issue(1, 1); issue(2, 2); issue(3, 3);
        for (int i = 0; i < m; i += 4) {
            #pragma unroll
            for (int s = 0; s < 4; s++) {
                if (i + s < m) {
                    compute(s);
                    issue(s, i + s + 4);
                }
            }
        }
    }
    float* dstp = (half ? aggr3 : aggr2) + (size_t)n * 64 + c2;
    *(float2*)dstp = acc;
}

// ===========================================================================
// Node MLP: out = epilogue( relu((xin+aggr) @ Wa + ba) @ Wb + bb )
// KIN -> 64 -> 64. 64 nodes per block, 256 threads, 4x4 register tiles.
// mode: 0 = none, 1 = relu, 2 = clip(-10, 10)
// ===========================================================================
template <int KIN>
__global__ __launch_bounds__(256) void node_mlp(
    const float* __restrict__ xin, const float* __restrict__ aggr,
    const float* __restrict__ Wa, const float* __restrict__ ba,
    const float* __restrict__ Wb, const float* __restrict__ bb,
    float* __restrict__ out, int mode)
{
    constexpr int S0 = KIN + 4;
    constexpr int K4 = KIN / 4;
    __shared__ float sWa[KIN * 64];
    __shared__ float sWb[64 * 64];
    __shared__ float sh[64 * S0];
    __shared__ float sba[64], sbb[64];
    int t = threadIdx.x;
    for (int i = t; i < KIN * 16; i += 256) ((float4*)sWa)[i] = ((const float4*)Wa)[i];
    for (int i = t; i < 1024; i += 256)     ((float4*)sWb)[i] = ((const float4*)Wb)[i];
    if (t < 64) { sba[t] = ba[t]; sbb[t] = bb[t]; }

    int nb = blockIdx.x << 6;
    for (int i = t; i < 64 * K4; i += 256) {
        int n = i / K4, k4 = i % K4;
        int node = nb + n;
        float4 v = make_float4(0.f, 0.f, 0.f, 0.f);
        if (node < NN) {
            float4 a = ((const float4*)(xin  + (size_t)node * KIN))[k4];
            float4 b = ((const float4*)(aggr + (size_t)node * KIN))[k4];
            v = make_float4(a.x + b.x, a.y + b.y, a.z + b.z, a.w + b.w);
        }
        *(float4*)&sh[n * S0 + (k4 << 2)] = v;
    }
    __syncthreads();

    int tx = t & 15, ty = t >> 4;
    int c0 = tx << 2, n0 = ty << 2;

    float4 b1 = *(const float4*)&sba[c0];
    float acc[4][4];
    #pragma unroll
    for (int i = 0; i < 4; i++) { acc[i][0] = b1.x; acc[i][1] = b1.y; acc[i][2] = b1.z; acc[i][3] = b1.w; }
    for (int k4 = 0; k4 < K4; k4++) {
        int k = k4 << 2;
        float4 w0 = *(const float4*)&sWa[((k + 0) << 6) + c0];
        float4 w1 = *(const float4*)&sWa[((k + 1) << 6) + c0];
        float4 w2 = *(const float4*)&sWa[((k + 2) << 6) + c0];
        float4 w3 = *(const float4*)&sWa[((k + 3) << 6) + c0];
        #pragma unroll
        for (int i = 0; i < 4; i++) {
            float4 hv = *(const float4*)&sh[(n0 + i) * S0 + k];
            acc[i][0] = fmaf(hv.x, w0.x, acc[i][0]); acc[i][1] = fmaf(hv.x, w0.y, acc[i][1]);
            acc[i][2] = fmaf(hv.x, w0.z, acc[i][2]); acc[i][3] = fmaf(hv.x, w0.w, acc[i][3]);
            acc[i][0] = fmaf(hv.y, w1.x, acc[i][0]); acc[i][1] = fmaf(hv.y, w1.y, acc[i][1]);
            acc[i][2] = fmaf(hv.y, w1.z, acc[i][2]); acc[i][3] = fmaf(hv.y, w1.w, acc[i][3]);
            acc[i][0] = fmaf(hv.z, w2.x, acc[i][0]); acc[i][1] = fmaf(hv.z, w2.y, acc[i][1]);
            acc[i][2] = fmaf(hv.z, w2.z, acc[i][2]); acc[i][3] = fmaf(hv.z, w2.w, acc[i][3]);
            acc[i][0] = fmaf(hv.w, w3.x, acc[i][0]); acc[i][1] = fmaf(hv.w, w3.y, acc[i][1]);
            acc[i][2] = fmaf(hv.w, w3.z, acc[i][2]); acc[i][3] = fmaf(hv.w, w3.w, acc[i][3]);
        }
    }
    __syncthreads();
    #pragma unroll
    for (int i = 0; i < 4; i++) {
        float4 v = make_float4(fmaxf(acc[i][0], 0.f), fmaxf(acc[i][1], 0.f),
                               fmaxf(acc[i][2], 0.f), fmaxf(acc[i][3], 0.f));
        *(float4*)&sh[(n0 + i) * 68 + c0] = v;
    }
    __syncthreads();

    float4 b2 = *(const float4*)&sbb[c0];
    float acc2[4][4];
    #pragma unroll
    for (int i = 0; i < 4; i++) { acc2[i][0] = b2.x; acc2[i][1] = b2.y; acc2[i][2] = b2.z; acc2[i][3] = b2.w; }
    for (int k4 = 0; k4 < 16; k4++) {
        int k = k4 << 2;
        float4 w0 = *(const float4*)&sWb[((k + 0) << 6) + c0];
        float4 w1 = *(const float4*)&sWb[((k + 1) << 6) + c0];
        float4 w2 = *(const float4*)&sWb[((k + 2) << 6) + c0];
        float4 w3 = *(const float4*)&sWb[((k + 3) << 6) + c0];
        #pragma unroll
        for (int i = 0; i < 4; i++) {
            float4 hv = *(const float4*)&sh[(n0 + i) * 68 + k];
            acc2[i][0] = fmaf(hv.x, w0.x, acc2[i][0]); acc2[i][1] = fmaf(hv.x, w0.y, acc2[i][1]);
            acc2[i][2] = fmaf(hv.x, w0.z, acc2[i][2]); acc2[i][3] = fmaf(hv.x, w0.w, acc2[i][3]);
            acc2[i][0] = fmaf(hv.y, w1.x, acc2[i][0]); acc2[i][1] = fmaf(hv.y, w1.y, acc2[i][1]);
            acc2[i][2] = fmaf(hv.y, w1.z, acc2[i][2]); acc2[i][3] = fmaf(hv.y, w1.w, acc2[i][3]);
            acc2[i][0] = fmaf(hv.z, w2.x, acc2[i][0]); acc2[i][1] = fmaf(hv.z, w2.y, acc2[i][1]);
            acc2[i][2] = fmaf(hv.z, w2.z, acc2[i][2]); acc2[i][3] = fmaf(hv.z, w2.w, acc2[i][3]);
            acc2[i][0] = fmaf(hv.w, w3.x, acc2[i][0]); acc2[i][1] = fmaf(hv.w, w3.y, acc2[i][1]);
            acc2[i][2] = fmaf(hv.w, w3.z, acc2[i][2]); acc2[i][3] = fmaf(hv.w, w3.w, acc2[i][3]);
        }
    }

    #pragma unroll
    for (int i = 0; i < 4; i++) {
        int node = nb + n0 + i;
        if (node >= NN) continue;
        float4 v = make_float4(acc2[i][0], acc2[i][1], acc2[i][2], acc2[i][3]);
        if (mode == 1) {
            v = make_float4(fmaxf(v.x, 0.f), fmaxf(v.y, 0.f), fmaxf(v.z, 0.f), fmaxf(v.w, 0.f));
        } else if (mode == 2) {
            v = make_float4(fminf(fmaxf(v.x, -10.f), 10.f), fminf(fmaxf(v.y, -10.f), 10.f),
                            fminf(fmaxf(v.z, -10.f), 10.f), fminf(fmaxf(v.w, -10.f), 10.f));
        }
        *(float4*)(out + (size_t)node * 64 + c0) = v;
    }
}

extern "C" void kernel_launch(void* const* d_in, const int* in_sizes, int n_in,
                              void* d_out, int out_size, void* d_ws, size_t ws_size,
                              hipStream_t stream)
{
    const float* x   = (const float*)d_in[0];
    const int*   ei  = (const int*)  d_in[1];
    const float* ea  = (const float*)d_in[2];
    const float* We1 = (const float*)d_in[3];
    const float* be1 = (const float*)d_in[4];
    const float* W1a = (const float*)d_in[5];
    const float* b1a = (const float*)d_in[6];
    const float* W1b = (const float*)d_in[7];
    const float* b1b = (const float*)d_in[8];
    const float* We2 = (const float*)d_in[9];
    const float* be2 = (const float*)d_in[10];
    const float* W2a = (const float*)d_in[11];
    const float* b2a = (const float*)d_in[12];
    const float* W2b = (const float*)d_in[13];
    const float* b2b = (const float*)d_in[14];
    const float* We3 = (const float*)d_in[15];
    const float* be3 = (const float*)d_in[16];
    const float* W3a = (const float*)d_in[17];
    const float* b3a = (const float*)d_in[18];
    const float* W3b = (const float*)d_in[19];
    const float* b3b = (const float*)d_in[20];

    float* out = (float*)d_out;
    float* ws = (float*)d_ws;
    // float scratch: aggr1 [12.8M] (later aliased by aggr2/aggr3), h [6.4M]
    float* aggr1 = ws;
    float* h     = ws + 12800000;
    float* aggr2 = ws;              // aliases aggr1 (dead after node_mlp<128>)
    float* aggr3 = ws + 6400000;
    // int scratch after 19.2M floats: off [NN+1], cur [NN], perm2 [2*NE]
    int* ibase = (int*)(ws + 19200000);
    int* off   = ibase;
    int* cur   = ibase + (NN + 1);
    int2* perm2 = (int2*)(ibase + (2 * NN + 2));

    // ---- CSR build (shared by conv1 and conv23) ----
    hipMemsetAsync(cur, 0, (size_t)NN * sizeof(int), stream);
    hist_dst<<<2048, 256, 0, stream>>>(ei, cur);
    scan_deg<<<1, 1024, 0, stream>>>(cur, off);   // cur becomes scatter cursor
    scatter_perm<<<2048, 256, 0, stream>>>(ei, cur, perm2);

    // ---- layer 1 ----
    conv1_gather<<<(NN + 3) / 4, 256, 0, stream>>>(x, ea, We1, be1, off, perm2, aggr1);
    node_mlp<128><<<(NN + 63) / 64, 256, 0, stream>>>(x, aggr1, W1a, b1a, W1b, b1b, h, 1);

    // ---- layers 2+3 (fused edge pass) ----
    conv23_gather<<<(NN + 3) / 4, 256, 0, stream>>>(h, ea, We2, be2, We3, be3,
                                                    off, perm2, aggr2, aggr3);
    node_mlp<64><<<(NN + 63) / 64, 256, 0, stream>>>(h, aggr2, W2a, b2a, W2b, b2b, out, 0);
    node_mlp<64><<<(NN + 63) / 64, 256, 0, stream>>>(h, aggr3, W3a, b3a, W3b, b3b,
                                                     out + (size_t)NN * 64, 2);
}